// Round 5
// baseline (309.872 us; speedup 1.0000x reference)
//
#include <hip/hip_runtime.h>
#include <hip/hip_bf16.h>
#include <stdint.h>

#define SEQ 2048
#define BAT 32
#define EDIM 1024
#define MROWS (SEQ*BAT)   // 65536

typedef __bf16 bf16x8 __attribute__((ext_vector_type(8)));
typedef float f32x16 __attribute__((ext_vector_type(16)));
typedef unsigned short u16x8 __attribute__((ext_vector_type(8)));

typedef __attribute__((address_space(3))) unsigned int lds_uint;
typedef const __attribute__((address_space(1))) unsigned int glb_uint;

__device__ __forceinline__ void async16(void* lds, const void* g) {
  __builtin_amdgcn_global_load_lds((glb_uint*)g, (lds_uint*)lds, 16, 0, 0);
}

__device__ __forceinline__ unsigned short f2bf(float f) {
  unsigned u = __builtin_bit_cast(unsigned, f);
  u = (u + 0x7FFFu + ((u >> 16) & 1u)) >> 16;
  return (unsigned short)u;
}
__device__ __forceinline__ float bf2f(unsigned short h) {
  return __builtin_bit_cast(float, (unsigned)h << 16);
}

// fast tanh: (e^{2x}-1)/(e^{2x}+1), clamped; ~7 VALU ops vs ~25 for ocml tanhf
__device__ __forceinline__ float fast_tanh(float x) {
  float xc = fminf(fmaxf(x, -9.f), 9.f);
  float e = __expf(2.f * xc);
  return (e - 1.f) * __builtin_amdgcn_rcpf(e + 1.f);
}

// ---------------- Kernel A: nv = g * v / ||v|| ----------------
__global__ void k_nv(const float* __restrict__ v, const float* __restrict__ g,
                     float* __restrict__ nv) {
  __shared__ float red[256];
  int t = threadIdx.x;
  float s = 0.f;
  for (int i = t; i < EDIM; i += 256) { float x = v[i]; s += x * x; }
  red[t] = s; __syncthreads();
  for (int o = 128; o > 0; o >>= 1) {
    if (t < o) red[t] += red[t + o];
    __syncthreads();
  }
  float scale = g[0] / sqrtf(red[0]);
  for (int i = t; i < EDIM; i += 256) nv[i] = v[i] * scale;
}

// ---------------- Kernel B: pqb[b][e] = query[b]·Wq[e] + bias[e] ----------------
__global__ void k_pqb(const float* __restrict__ query, const float* __restrict__ Wq,
                      const float* __restrict__ bias, float* __restrict__ pqb) {
  __shared__ float wq[1024];
  int e = blockIdx.x;
  int t = threadIdx.x;
  reinterpret_cast<float4*>(wq)[t] =
      reinterpret_cast<const float4*>(Wq + (size_t)e * EDIM)[t];
  __syncthreads();
  int w = t >> 6, lane = t & 63;
  float be = bias[e];
  for (int bb = 0; bb < 8; ++bb) {
    int b_ = w * 8 + bb;
    const float4* q4 = reinterpret_cast<const float4*>(query + (size_t)b_ * EDIM) + lane * 4;
    const float4* w4 = reinterpret_cast<const float4*>(wq) + lane * 4;
    float s = 0.f;
#pragma unroll
    for (int j = 0; j < 4; ++j) {
      float4 a = q4[j], c = w4[j];
      s += a.x * c.x + a.y * c.y + a.z * c.z + a.w * c.w;
    }
#pragma unroll
    for (int m = 32; m > 0; m >>= 1) s += __shfl_xor(s, m);
    if (lane == 0) pqb[(size_t)b_ * EDIM + e] = s + be;
  }
}

// ---------------- Kernel C: fp32 -> bf16 convert, 8 elems/thread ----------------
__global__ void k_cvt(const float* __restrict__ in, unsigned short* __restrict__ out,
                      long long n8) {
  long long i = (long long)blockIdx.x * blockDim.x + threadIdx.x;
  long long stride = (long long)gridDim.x * blockDim.x;
  for (; i < n8; i += stride) {
    const float4* p = reinterpret_cast<const float4*>(in + i * 8);
    float4 a = p[0], b = p[1];
    u16x8 r;
    r[0] = f2bf(a.x); r[1] = f2bf(a.y); r[2] = f2bf(a.z); r[3] = f2bf(a.w);
    r[4] = f2bf(b.x); r[5] = f2bf(b.y); r[6] = f2bf(b.z); r[7] = f2bf(b.w);
    *reinterpret_cast<u16x8*>(out + i * 8) = r;
  }
}

// ---------------- Kernel D: 256x256-tile pipelined GEMM (32x32x16 MFMA) ----------------
// 8 waves (2M x 4N), BK=64, double-buffered 128 KiB LDS, T2 XOR swizzle,
// issue-early gload_lds staging, hoisted addressing (1 xor + imm-offset per read).
__global__ __launch_bounds__(512, 1) void k_gemm(
    const unsigned short* __restrict__ A,   // [MROWS][1024] bf16 bits
    const unsigned short* __restrict__ Bm,  // [1024][1024] bf16 bits
    const float* __restrict__ pqb,          // [32][1024]
    const float* __restrict__ nv,           // [1024]
    float* __restrict__ part)               // [4][MROWS]
{
  // slot s: A at s*65536, B at s*65536+32768; partLds at 131072
  __shared__ char smem[2 * 65536 + 4 * 256 * 4];

  const int tid = threadIdx.x;
  const int lane = tid & 63;
  const int wid = tid >> 6;
  const int wm = wid >> 2;                  // 0..1
  const int wn = wid & 3;                   // 0..3
  const int l31 = lane & 31;
  const int hi = lane >> 5;

  // XCD-chunked mapping: 4 ni-siblings of one A-panel adjacent on one XCD.
  const int bid = blockIdx.x;               // 0..1023
  const int xcd = bid & 7;
  const int j = bid >> 3;                   // 0..127
  const int mi_blk = xcd * 32 + (j >> 2);
  const int ni_blk = j & 3;
  const size_t m0 = (size_t)mi_blk * 256;
  const int n0 = ni_blk * 256;

  float* partLds = (float*)(smem + 131072);

  f32x16 acc[4][2];
#pragma unroll
  for (int i = 0; i < 4; ++i)
#pragma unroll
    for (int jj = 0; jj < 2; ++jj) acc[i][jj] = (f32x16)(0.f);

  // ---- hoisted stage addressing ----
  // chunk = i*512+tid -> row = i*64 + (tid>>3), col c = tid&7;
  // source col inverse-swizzled: csrc = (tid&7) ^ ((tid>>3)&7)  (constant/thread)
  const int csrc = (tid & 7) ^ ((tid >> 3) & 7);
  const unsigned short* gA[4];
  const unsigned short* gB[4];
#pragma unroll
  for (int i = 0; i < 4; ++i) {
    int row = i * 64 + (tid >> 3);
    gA[i] = A + (m0 + (size_t)row) * 1024 + csrc * 8;
    gB[i] = Bm + (size_t)(n0 + row) * 1024 + csrc * 8;
  }
  const int ldsOffA = tid * 16;            // within A region (chunk*16, i step = 8192)
  const int ldsOffB = 32768 + tid * 16;

  // ---- hoisted LDS read addressing ----
  // read G[row][cg] at LDS row*128 + (cg ^ (row&7))*16 ; row&7 == lane&7
  // cg = ks*2 + hi  ->  byte addr = rd0 ^ (ks<<5), frag row step = +4096
  const int swz = ((hi ^ (lane & 7)) << 4);
  const int rdA = (wm * 128 + l31) * 128 + swz;
  const int rdB = 32768 + (wn * 64 + l31) * 128 + swz;

  auto stageA = [&](char* sl) {
#pragma unroll
    for (int i = 0; i < 4; ++i)
      async16(sl + ldsOffA + i * 8192, gA[i]);
  };
  auto stageB = [&](char* sl) {
#pragma unroll
    for (int i = 0; i < 4; ++i)
      async16(sl + ldsOffB + i * 8192, gB[i]);
  };
  auto bump = [&]() {
#pragma unroll
    for (int i = 0; i < 4; ++i) { gA[i] += 64; gB[i] += 64; }
  };

  char* buf0 = smem;
  char* buf1 = smem + 65536;

  stageA(buf0);
  stageB(buf0);
  bump();
  __syncthreads();   // drain prologue loads

  // body: compute on cb, prefetch tile into nb (if pf)
  auto body = [&](char* cb, char* nb, bool pf) {
    if (pf) stageA(nb);   // issue early: flies under the MFMA phase
#pragma unroll
    for (int ks = 0; ks < 4; ++ks) {
      const int x = ks << 5;
      bf16x8 af[4], bf[2];
#pragma unroll
      for (int fm = 0; fm < 4; ++fm)
        af[fm] = *reinterpret_cast<const bf16x8*>(cb + ((rdA ^ x) + fm * 4096));
#pragma unroll
      for (int fn = 0; fn < 2; ++fn)
        bf[fn] = *reinterpret_cast<const bf16x8*>(cb + ((rdB ^ x) + fn * 4096));

      if (ks == 1 && pf) stageB(nb);

      __builtin_amdgcn_s_setprio(1);
#pragma unroll
      for (int fm = 0; fm < 4; ++fm)
#pragma unroll
        for (int fn = 0; fn < 2; ++fn)
          acc[fm][fn] = __builtin_amdgcn_mfma_f32_32x32x16_bf16(af[fm], bf[fn], acc[fm][fn], 0, 0, 0);
      __builtin_amdgcn_s_setprio(0);
    }
    if (pf) bump();
    __syncthreads();  // vmcnt(0)+barrier: next tile resident, buffers swappable
  };

#pragma unroll 1
  for (int tt = 0; tt < 8; ++tt) {
    body(buf0, buf1, true);
    body(buf1, buf0, tt < 7);
  }

  // Epilogue (32x32 C/D layout, m74/m101): n = l31 (+32*fn +64*wn +n0),
  // m = (r&3) + 8*(r>>2) + 4*hi (+32*fm +128*wm)
  float nve[2];
#pragma unroll
  for (int fn = 0; fn < 2; ++fn) nve[fn] = nv[n0 + wn * 64 + fn * 32 + l31];

#pragma unroll
  for (int fm = 0; fm < 4; ++fm) {
#pragma unroll
    for (int r = 0; r < 16; ++r) {
      int b_ = (r & 3) + 8 * (r >> 2) + 4 * hi;       // = m_loc & 31
      int m_loc = wm * 128 + fm * 32 + b_;
      const float* pq = pqb + (size_t)b_ * EDIM + n0 + wn * 64 + l31;
      float s = nve[0] * fast_tanh(acc[fm][0][r] + pq[0]) +
                nve[1] * fast_tanh(acc[fm][1][r] + pq[32]);
      s += __shfl_xor(s, 1);
      s += __shfl_xor(s, 2);
      s += __shfl_xor(s, 4);
      s += __shfl_xor(s, 8);
      s += __shfl_xor(s, 16);
      if (l31 == 0) partLds[wn * 256 + m_loc] = s;
    }
  }
  __syncthreads();
  if (tid < 256)
    part[(size_t)ni_blk * MROWS + m0 + tid] =
        partLds[tid] + partLds[256 + tid] + partLds[512 + tid] + partLds[768 + tid];
}

// ---------------- Kernel E: reduce 4 chunks + mask + softmax over s ----------------
__global__ void k_softmax(const float* __restrict__ part,          // [4][MROWS]
                          const unsigned char* __restrict__ mask,  // [S][B]
                          float* __restrict__ scores,              // [MROWS]
                          float* __restrict__ out_attn)            // d_out + 32768
{
  int b_ = blockIdx.x;
  int t = threadIdx.x;
  __shared__ float red[256];
  float sc[8];
  float mx = -1e30f;
#pragma unroll
  for (int i = 0; i < 8; ++i) {
    int s_ = t + i * 256;
    size_t r = (size_t)s_ * BAT + b_;
    float v = 0.f;
#pragma unroll
    for (int c = 0; c < 4; ++c) v += part[(size_t)c * MROWS + r];
    if (mask[r]) v = -1e30f;
    sc[i] = v;
    mx = fmaxf(mx, v);
  }
  red[t] = mx; __syncthreads();
  for (int o = 128; o > 0; o >>= 1) {
    if (t < o) red[t] = fmaxf(red[t], red[t + o]);
    __syncthreads();
  }
  mx = red[0];
  __syncthreads();
  float sum = 0.f;
#pragma unroll
  for (int i = 0; i < 8; ++i) { sc[i] = expf(sc[i] - mx); sum += sc[i]; }
  red[t] = sum; __syncthreads();
  for (int o = 128; o > 0; o >>= 1) {
    if (t < o) red[t] += red[t + o];
    __syncthreads();
  }
  float inv = 1.f / red[0];
#pragma unroll
  for (int i = 0; i < 8; ++i) {
    int s_ = t + i * 256;
    size_t r = (size_t)s_ * BAT + b_;
    float w = sc[i] * inv;
    scores[r] = w;
    out_attn[r] = w;
    out_attn[MROWS + r] = w;
  }
}

// ---------------- Kernel F: context partials over s-chunks ----------------
__global__ void k_ctx(const unsigned short* __restrict__ Vb,  // [MROWS][1024] bf16
                      const float* __restrict__ scores,       // [MROWS]
                      float* __restrict__ pctx)               // [16][BAT][1024]
{
  int b_ = blockIdx.x;   // 0..31
  int sch = blockIdx.y;  // 0..7
  int t = threadIdx.x;
  int d8 = t & 127;
  int sr = t >> 7;
  float acc[8];
#pragma unroll
  for (int j = 0; j < 8; ++j) acc[j] = 0.f;
  int s0 = sch * 256;
  for (int i = 0; i < 128; ++i) {
    int s_ = s0 + i * 2 + sr;
    size_t r = (size_t)s_ * BAT + b_;
    float w = scores[r];
    u16x8 v = *reinterpret_cast<const u16x8*>(Vb + r * 1024 + d8 * 8);
#pragma unroll
    for (int j = 0; j < 8; ++j) acc[j] += w * bf2f(v[j]);
  }
  float* dst = pctx + ((size_t)(sch * 2 + sr) * BAT + b_) * 1024 + d8 * 8;
#pragma unroll
  for (int j = 0; j < 8; ++j) dst[j] = acc[j];
}

// ---------------- Kernel G: final context reduce ----------------
__global__ void k_ctx_reduce(const float* __restrict__ pctx, float* __restrict__ out) {
  int i = blockIdx.x * 256 + threadIdx.x;  // 0..32767
  float s = 0.f;
#pragma unroll
  for (int c = 0; c < 16; ++c) s += pctx[(size_t)c * 32768 + i];
  out[i] = s;
}

extern "C" void kernel_launch(void* const* d_in, const int* in_sizes, int n_in,
                              void* d_out, int out_size, void* d_ws, size_t ws_size,
                              hipStream_t stream) {
  const float* query = (const float*)d_in[0];
  const float* value = (const float*)d_in[1];
  const float* Wq    = (const float*)d_in[2];
  const float* Wv    = (const float*)d_in[3];
  const float* v     = (const float*)d_in[4];
  const float* bias  = (const float*)d_in[5];
  const float* g     = (const float*)d_in[6];
  const unsigned char* mask = (const unsigned char*)d_in[7];
  float* out = (float*)d_out;

  char* ws = (char*)d_ws;
  unsigned short* Vb  = (unsigned short*)ws;                        // 128 MB
  unsigned short* Wvb = (unsigned short*)(ws + (size_t)134217728);  // 2 MB
  float* pqb    = (float*)(ws + (size_t)134217728 + 2097152);       // 128 KB
  float* nv     = pqb + 32 * 1024;                                  // 4 KB
  float* part   = nv + 1024;                                        // 4*65536*4 = 1 MB
  float* scores = part + 4 * MROWS;                                 // 256 KB
  float* pctx   = scores + MROWS;                                   // 2 MB

  k_nv<<<1, 256, 0, stream>>>(v, g, nv);
  k_pqb<<<1024, 256, 0, stream>>>(query, Wq, bias, pqb);
  k_cvt<<<2048, 256, 0, stream>>>(value, Vb, (long long)(65536LL * 1024 / 8));
  k_cvt<<<512, 256, 0, stream>>>(Wv, Wvb, (long long)(1024LL * 1024 / 8));
  k_gemm<<<1024, 512, 0, stream>>>(Vb, Wvb, pqb, nv, part);
  k_softmax<<<32, 256, 0, stream>>>(part, mask, scores, out + 32768);
  dim3 gf(32, 8);
  k_ctx<<<gf, 256, 0, stream>>>(Vb, scores, pctx);
  k_ctx_reduce<<<128, 256, 0, stream>>>(pctx, out);
}

// Round 6
// 286.378 us; speedup vs baseline: 1.0820x; 1.0820x over previous
//
#include <hip/hip_runtime.h>
#include <hip/hip_bf16.h>
#include <stdint.h>

#define SEQ 2048
#define BAT 32
#define EDIM 1024
#define MROWS (SEQ*BAT)   // 65536

typedef __bf16 bf16x8 __attribute__((ext_vector_type(8)));
typedef float f32x4 __attribute__((ext_vector_type(4)));
typedef unsigned short u16x8 __attribute__((ext_vector_type(8)));

typedef __attribute__((address_space(3))) unsigned int lds_uint;
typedef const __attribute__((address_space(1))) unsigned int glb_uint;

#define WAITV(n) asm volatile("s_waitcnt vmcnt(" #n ")" ::: "memory")

__device__ __forceinline__ void async16(void* lds, const void* g) {
  __builtin_amdgcn_global_load_lds((glb_uint*)g, (lds_uint*)lds, 16, 0, 0);
}

__device__ __forceinline__ unsigned short f2bf(float f) {
  unsigned u = __builtin_bit_cast(unsigned, f);
  u = (u + 0x7FFFu + ((u >> 16) & 1u)) >> 16;
  return (unsigned short)u;
}
__device__ __forceinline__ float bf2f(unsigned short h) {
  return __builtin_bit_cast(float, (unsigned)h << 16);
}

// fast tanh: (e^{2x}-1)/(e^{2x}+1), clamped; ~7 VALU ops vs ~25 for ocml tanhf
__device__ __forceinline__ float fast_tanh(float x) {
  float xc = fminf(fmaxf(x, -9.f), 9.f);
  float e = __expf(2.f * xc);
  return (e - 1.f) * __builtin_amdgcn_rcpf(e + 1.f);
}

// ---------------- Kernel A: nv = g * v / ||v|| ----------------
__global__ void k_nv(const float* __restrict__ v, const float* __restrict__ g,
                     float* __restrict__ nv) {
  __shared__ float red[256];
  int t = threadIdx.x;
  float s = 0.f;
  for (int i = t; i < EDIM; i += 256) { float x = v[i]; s += x * x; }
  red[t] = s; __syncthreads();
  for (int o = 128; o > 0; o >>= 1) {
    if (t < o) red[t] += red[t + o];
    __syncthreads();
  }
  float scale = g[0] / sqrtf(red[0]);
  for (int i = t; i < EDIM; i += 256) nv[i] = v[i] * scale;
}

// ---------------- Kernel B: pqb[b][e] = query[b]·Wq[e] + bias[e] ----------------
__global__ void k_pqb(const float* __restrict__ query, const float* __restrict__ Wq,
                      const float* __restrict__ bias, float* __restrict__ pqb) {
  __shared__ float wq[1024];
  int e = blockIdx.x;
  int t = threadIdx.x;
  reinterpret_cast<float4*>(wq)[t] =
      reinterpret_cast<const float4*>(Wq + (size_t)e * EDIM)[t];
  __syncthreads();
  int w = t >> 6, lane = t & 63;
  float be = bias[e];
  for (int bb = 0; bb < 8; ++bb) {
    int b_ = w * 8 + bb;
    const float4* q4 = reinterpret_cast<const float4*>(query + (size_t)b_ * EDIM) + lane * 4;
    const float4* w4 = reinterpret_cast<const float4*>(wq) + lane * 4;
    float s = 0.f;
#pragma unroll
    for (int j = 0; j < 4; ++j) {
      float4 a = q4[j], c = w4[j];
      s += a.x * c.x + a.y * c.y + a.z * c.z + a.w * c.w;
    }
#pragma unroll
    for (int m = 32; m > 0; m >>= 1) s += __shfl_xor(s, m);
    if (lane == 0) pqb[(size_t)b_ * EDIM + e] = s + be;
  }
}

// ---------------- Kernel C: fp32 -> bf16 convert, 8 elems/thread ----------------
__global__ void k_cvt(const float* __restrict__ in, unsigned short* __restrict__ out,
                      long long n8) {
  long long i = (long long)blockIdx.x * blockDim.x + threadIdx.x;
  long long stride = (long long)gridDim.x * blockDim.x;
  for (; i < n8; i += stride) {
    const float4* p = reinterpret_cast<const float4*>(in + i * 8);
    float4 a = p[0], b = p[1];
    u16x8 r;
    r[0] = f2bf(a.x); r[1] = f2bf(a.y); r[2] = f2bf(a.z); r[3] = f2bf(a.w);
    r[4] = f2bf(b.x); r[5] = f2bf(b.y); r[6] = f2bf(b.z); r[7] = f2bf(b.w);
    *reinterpret_cast<u16x8*>(out + i * 8) = r;
  }
}

// ---------------- Kernel D: 256x256 GEMM, counted-vmcnt half-tile pipeline ----------------
// 8 waves (2M x 4N), 16x16x32 MFMA. K split into 32 halves of K=32.
// 4 half-buffers of 32 KiB (A 16K + B 16K); stage 3 halves ahead.
// Per half-step: vmcnt(8) [counted, never 0 in main loop] -> raw s_barrier ->
// stage half h+3 -> 12 ds_read_b128 -> setprio + 32 MFMA.
// T2 XOR swizzle adapted to 64B rows: stored pos = cg ^ (row&3).
__global__ __launch_bounds__(512, 1) void k_gemm(
    const unsigned short* __restrict__ A,   // [MROWS][1024] bf16 bits
    const unsigned short* __restrict__ Bm,  // [1024][1024] bf16 bits
    const float* __restrict__ pqb,          // [32][1024]
    const float* __restrict__ nv,           // [1024]
    float* __restrict__ part)               // [4][MROWS]
{
  __shared__ char smem[4 * 32768 + 4 * 256 * 4];

  const int tid = threadIdx.x;
  const int lane = tid & 63;
  const int wid = tid >> 6;
  const int wm = wid >> 2;                  // 0..1
  const int wn = wid & 3;                   // 0..3

  // XCD-chunked mapping: 4 ni-siblings of one A-panel adjacent on one XCD.
  const int bid = blockIdx.x;               // 0..1023
  const int xcd = bid & 7;
  const int j = bid >> 3;                   // 0..127
  const int mi_blk = xcd * 32 + (j >> 2);
  const int ni_blk = j & 3;
  const size_t m0 = (size_t)mi_blk * 256;
  const int n0 = ni_blk * 256;

  float* partLds = (float*)(smem + 131072);

  f32x4 acc[8][4];
#pragma unroll
  for (int i = 0; i < 8; ++i)
#pragma unroll
    for (int jj = 0; jj < 4; ++jj) acc[i][jj] = f32x4{0.f, 0.f, 0.f, 0.f};

  // ---- staging addressing (2 A-chunks + 2 B-chunks per thread per half) ----
  // chunk ci = tid, tid+512: row = ci>>2 (0..255), pos p = tid&3;
  // source col group inverse-swizzled: csrc = p ^ (row&3)  (same for both ci)
  const int csrc = (tid & 3) ^ ((tid >> 2) & 3);
  const int row0 = tid >> 2;
  const unsigned short* gA0 = A + (m0 + (size_t)row0) * 1024 + csrc * 8;
  const unsigned short* gA1 = gA0 + 128 * 1024;
  const unsigned short* gB0 = Bm + (size_t)(n0 + row0) * 1024 + csrc * 8;
  const unsigned short* gB1 = gB0 + 128 * 1024;
  const int dst0 = tid * 16;

  auto stage = [&](char* buf) {
    async16(buf + dst0, gA0);
    async16(buf + 8192 + dst0, gA1);
    async16(buf + 16384 + dst0, gB0);
    async16(buf + 24576 + dst0, gB1);
    gA0 += 32; gA1 += 32; gB0 += 32; gB1 += 32;   // next K-half
  };

  // ---- LDS read addressing ----
  // A half region: [256 rows][32 k] bf16, row stride 64B, 4 chunks/row.
  // frag: row = wm*128 + mi*16 + (lane&15); cg = lane>>4; pos = cg ^ (row&3)
  const int rA = lane & 15;
  const int swz = (((lane >> 4) ^ (lane & 3)) << 4);
  const int rdA = (wm * 128 + rA) * 64 + swz;
  const int rdB = 16384 + (wn * 64 + rA) * 64 + swz;

  auto half_step = [&](char* cb, char* sb) {
    __builtin_amdgcn_s_barrier();            // all waves: half(cb) resident, prev reads done
    if (sb) stage(sb);                       // stage half h+3 (flies under MFMA)
    bf16x8 af[8], bf[4];
#pragma unroll
    for (int mi = 0; mi < 8; ++mi)
      af[mi] = *reinterpret_cast<const bf16x8*>(cb + rdA + mi * 1024);
#pragma unroll
    for (int fn = 0; fn < 4; ++fn)
      bf[fn] = *reinterpret_cast<const bf16x8*>(cb + rdB + fn * 1024);
    __builtin_amdgcn_s_setprio(1);
#pragma unroll
    for (int mi = 0; mi < 8; ++mi)
#pragma unroll
      for (int fn = 0; fn < 4; ++fn)
        acc[mi][fn] = __builtin_amdgcn_mfma_f32_16x16x32_bf16(af[mi], bf[fn], acc[mi][fn], 0, 0, 0);
    __builtin_amdgcn_s_setprio(0);
  };

  char* b0 = smem;
  char* b1 = smem + 32768;
  char* b2 = smem + 65536;
  char* b3 = smem + 98304;

  stage(b0); stage(b1); stage(b2);           // prologue: halves 0,1,2 in flight

#pragma unroll 1
  for (int it = 0; it < 7; ++it) {           // halves 0..27
    WAITV(8); half_step(b0, b3);
    WAITV(8); half_step(b1, b0);
    WAITV(8); half_step(b2, b1);
    WAITV(8); half_step(b3, b2);
  }
  WAITV(8); half_step(b0, b3);               // h=28, stage h=31
  WAITV(8); half_step(b1, nullptr);          // h=29
  WAITV(4); half_step(b2, nullptr);          // h=30
  WAITV(0); half_step(b3, nullptr);          // h=31

  // Epilogue: C row = wm*128+mi*16+(lane>>4)*4+r, col = n0+wn*64+fn*16+(lane&15)
  const int cgrp = lane >> 4;
  const int ccol = lane & 15;
  float nve[4];
#pragma unroll
  for (int fn = 0; fn < 4; ++fn) nve[fn] = nv[n0 + wn * 64 + fn * 16 + ccol];

#pragma unroll
  for (int mi = 0; mi < 8; ++mi) {
#pragma unroll
    for (int r = 0; r < 4; ++r) {
      int rloc = wm * 128 + mi * 16 + cgrp * 4 + r;
      int b_ = rloc & 31;   // m0 is a multiple of 256
      const float* pq = pqb + (size_t)b_ * EDIM + n0 + wn * 64 + ccol;
      float s = 0.f;
#pragma unroll
      for (int fn = 0; fn < 4; ++fn)
        s += nve[fn] * fast_tanh(acc[mi][fn][r] + pq[fn * 16]);
      s += __shfl_xor(s, 1);
      s += __shfl_xor(s, 2);
      s += __shfl_xor(s, 4);
      s += __shfl_xor(s, 8);
      if (ccol == 0) partLds[wn * 256 + rloc] = s;
    }
  }
  __syncthreads();
  if (tid < 256)
    part[(size_t)ni_blk * MROWS + m0 + tid] =
        partLds[tid] + partLds[256 + tid] + partLds[512 + tid] + partLds[768 + tid];
}

// ---------------- Kernel E: reduce 4 chunks + mask + softmax over s ----------------
__global__ void k_softmax(const float* __restrict__ part,          // [4][MROWS]
                          const unsigned char* __restrict__ mask,  // [S][B]
                          float* __restrict__ scores,              // [MROWS]
                          float* __restrict__ out_attn)            // d_out + 32768
{
  int b_ = blockIdx.x;
  int t = threadIdx.x;
  __shared__ float red[256];
  float sc[8];
  float mx = -1e30f;
#pragma unroll
  for (int i = 0; i < 8; ++i) {
    int s_ = t + i * 256;
    size_t r = (size_t)s_ * BAT + b_;
    float v = 0.f;
#pragma unroll
    for (int c = 0; c < 4; ++c) v += part[(size_t)c * MROWS + r];
    if (mask[r]) v = -1e30f;
    sc[i] = v;
    mx = fmaxf(mx, v);
  }
  red[t] = mx; __syncthreads();
  for (int o = 128; o > 0; o >>= 1) {
    if (t < o) red[t] = fmaxf(red[t], red[t + o]);
    __syncthreads();
  }
  mx = red[0];
  __syncthreads();
  float sum = 0.f;
#pragma unroll
  for (int i = 0; i < 8; ++i) { sc[i] = expf(sc[i] - mx); sum += sc[i]; }
  red[t] = sum; __syncthreads();
  for (int o = 128; o > 0; o >>= 1) {
    if (t < o) red[t] += red[t + o];
    __syncthreads();
  }
  float inv = 1.f / red[0];
#pragma unroll
  for (int i = 0; i < 8; ++i) {
    int s_ = t + i * 256;
    size_t r = (size_t)s_ * BAT + b_;
    float w = sc[i] * inv;
    scores[r] = w;
    out_attn[r] = w;
    out_attn[MROWS + r] = w;
  }
}

// ---------------- Kernel F: context partials over s-chunks ----------------
__global__ void k_ctx(const unsigned short* __restrict__ Vb,  // [MROWS][1024] bf16
                      const float* __restrict__ scores,       // [MROWS]
                      float* __restrict__ pctx)               // [16][BAT][1024]
{
  int b_ = blockIdx.x;   // 0..31
  int sch = blockIdx.y;  // 0..7
  int t = threadIdx.x;
  int d8 = t & 127;
  int sr = t >> 7;
  float acc[8];
#pragma unroll
  for (int j = 0; j < 8; ++j) acc[j] = 0.f;
  int s0 = sch * 256;
  for (int i = 0; i < 128; ++i) {
    int s_ = s0 + i * 2 + sr;
    size_t r = (size_t)s_ * BAT + b_;
    float w = scores[r];
    u16x8 v = *reinterpret_cast<const u16x8*>(Vb + r * 1024 + d8 * 8);
#pragma unroll
    for (int j = 0; j < 8; ++j) acc[j] += w * bf2f(v[j]);
  }
  float* dst = pctx + ((size_t)(sch * 2 + sr) * BAT + b_) * 1024 + d8 * 8;
#pragma unroll
  for (int j = 0; j < 8; ++j) dst[j] = acc[j];
}

// ---------------- Kernel G: final context reduce ----------------
__global__ void k_ctx_reduce(const float* __restrict__ pctx, float* __restrict__ out) {
  int i = blockIdx.x * 256 + threadIdx.x;  // 0..32767
  float s = 0.f;
#pragma unroll
  for (int c = 0; c < 16; ++c) s += pctx[(size_t)c * 32768 + i];
  out[i] = s;
}

extern "C" void kernel_launch(void* const* d_in, const int* in_sizes, int n_in,
                              void* d_out, int out_size, void* d_ws, size_t ws_size,
                              hipStream_t stream) {
  const float* query = (const float*)d_in[0];
  const float* value = (const float*)d_in[1];
  const float* Wq    = (const float*)d_in[2];
  const float* Wv    = (const float*)d_in[3];
  const float* v     = (const float*)d_in[4];
  const float* bias  = (const float*)d_in[5];
  const float* g     = (const float*)d_in[6];
  const unsigned char* mask = (const unsigned char*)d_in[7];
  float* out = (float*)d_out;

  char* ws = (char*)d_ws;
  unsigned short* Vb  = (unsigned short*)ws;                        // 128 MB
  unsigned short* Wvb = (unsigned short*)(ws + (size_t)134217728);  // 2 MB
  float* pqb    = (float*)(ws + (size_t)134217728 + 2097152);       // 128 KB
  float* nv     = pqb + 32 * 1024;                                  // 4 KB
  float* part   = nv + 1024;                                        // 4*65536*4 = 1 MB
  float* scores = part + 4 * MROWS;                                 // 256 KB
  float* pctx   = scores + MROWS;                                   // 2 MB

  k_nv<<<1, 256, 0, stream>>>(v, g, nv);
  k_pqb<<<1024, 256, 0, stream>>>(query, Wq, bias, pqb);
  k_cvt<<<2048, 256, 0, stream>>>(value, Vb, (long long)(65536LL * 1024 / 8));
  k_cvt<<<512, 256, 0, stream>>>(Wv, Wvb, (long long)(1024LL * 1024 / 8));
  k_gemm<<<1024, 512, 0, stream>>>(Vb, Wvb, pqb, nv, part);
  k_softmax<<<32, 256, 0, stream>>>(part, mask, scores, out + 32768);
  dim3 gf(32, 8);
  k_ctx<<<gf, 256, 0, stream>>>(Vb, scores, pctx);
  k_ctx_reduce<<<128, 256, 0, stream>>>(pctx, out);
}